// Round 5
// baseline (778.971 us; speedup 1.0000x reference)
//
#include <hip/hip_runtime.h>

// Problem constants
#define B_     32
#define NOTES_ 78
#define T_     128
#define IN_    80
#define H_     128
#define NSEQ_  (B_*NOTES_)    // 2496
#define MBLK   16             // sequences per block (stage 1)
#define NBLK1  (NSEQ_/MBLK)   // 156
#define SEQ2_  (B_*T_)        // 4096 note-LSTM sequences
#define NROWS  (SEQ2_*NOTES_) // 319488 rows of th

typedef __attribute__((ext_vector_type(8))) short short8;   // 8 x bf16 (4 VGPRs)
typedef __attribute__((ext_vector_type(4))) float f32x4;

__device__ __forceinline__ float bf2f(unsigned short v) {
    unsigned u = ((unsigned)v) << 16; float f; __builtin_memcpy(&f, &u, 4); return f;
}
__device__ __forceinline__ unsigned short f2bf(float f) {
    unsigned u; __builtin_memcpy(&u, &f, 4);
    u += 0x7fffu + ((u >> 16) & 1u);          // RNE
    return (unsigned short)(u >> 16);
}
__device__ __forceinline__ short8 pack8(const float* p) {
    short8 r;
    #pragma unroll
    for (int k = 0; k < 8; ++k) r[k] = (short)f2bf(p[k]);
    return r;
}
// v_rcp_f32-based sigmoid/tanh: ~1 ulp rcp, avoids IEEE divide sequences
__device__ __forceinline__ float sigm(float x) {
    return __builtin_amdgcn_rcpf(1.f + __expf(-x));
}
__device__ __forceinline__ float tanh_(float x) {
    return 2.f * __builtin_amdgcn_rcpf(1.f + __expf(-2.f * x)) - 1.f;
}

// ---------------------------------------------------------------------------
// Time LSTM. One block (8 waves, 512 thr) owns MBLK=16 sequences for all T.
// Wave w owns h-cols [16w,16w+16): its 4 MFMA col-tiles are the i/f/g/o gate
// tiles of those cols, so after the MFMA phase thread (m16,quad) holds all 4
// gates for h-col 16w+m16, rows quad*4..+3 — elementwise is register-only.
// Single barrier per step (sH ping-pong removes the WAR race); th(t-1) stored
// after the barrier so its vmcnt drain overlaps the next MFMA phase; x(t+1)
// (f32, packed to bf16 at use) prefetched at step top.
// ---------------------------------------------------------------------------
__global__ __launch_bounds__(512, 2) void time_lstm_kernel(
    const float* __restrict__ x,     // [NSEQ][T][IN] f32
    const float* __restrict__ Wih,   // [512][80]  f32
    const float* __restrict__ Whh,   // [512][128] f32
    const float* __restrict__ bih,   // [512] f32
    const float* __restrict__ bhh,   // [512] f32
    unsigned short* __restrict__ th) // [B][T][NOTES][H] bf16 (ws)
{
    __shared__ unsigned short sH[2][MBLK * 136];   // ping-pong, stride 136

    const int tid  = threadIdx.x;
    const int wave = tid >> 6, lane = tid & 63;
    const int m16  = lane & 15, quad = lane >> 4;
    const int seq0 = blockIdx.x * MBLK;
    const int c    = wave * 16 + m16;              // h-col owned by this thread

    for (int i = tid; i < 2 * MBLK * 136; i += 512)
        ((unsigned short*)sH)[i] = 0;              // h0 = 0 (both buffers)

    // ---- weight B-fragments: 4 gate tiles x (3+4) K-frags = 28 (112 VGPR) --
    const short8 zero8 = (short8){0,0,0,0,0,0,0,0};
    short8 wf[4][3], hf[4][4];
    #pragma unroll
    for (int g = 0; g < 4; ++g) {
        const int n = g * 128 + c;
        #pragma unroll
        for (int kt = 0; kt < 3; ++kt) {
            const int k = kt * 32 + quad * 8;
            wf[g][kt] = (k < IN_) ? pack8(Wih + n * IN_ + k) : zero8;
        }
        #pragma unroll
        for (int kt = 0; kt < 4; ++kt)
            hf[g][kt] = pack8(Whh + n * H_ + kt * 32 + quad * 8);
    }

    const float b_i = bih[      c] + bhh[      c];
    const float b_f = bih[128 + c] + bhh[128 + c];
    const float b_g = bih[256 + c] + bhh[256 + c];
    const float b_o = bih[384 + c] + bhh[384 + c];

    float    cst[4] = {0.f, 0.f, 0.f, 0.f};
    unsigned obase[4];
    #pragma unroll
    for (int r = 0; r < 4; ++r) {
        const int sq = seq0 + quad * 4 + r;
        const int bb = sq / NOTES_;
        const int nn = sq - bb * NOTES_;
        obase[r] = (unsigned)bb * (T_ * NOTES_ * H_) + (unsigned)nn * H_ + (unsigned)c;
    }

    // x rows for A-fragments: row m16 (seq seq0+m16), k = quad*8 (+0/32/64)
    const float* xrow = x + (size_t)(seq0 + m16) * T_ * IN_ + quad * 8;

    // load x(0) as f32 (packed at use)
    float nxf[24];
    #pragma unroll
    for (int k = 0; k < 8; ++k) {
        nxf[k]      = xrow[k];
        nxf[8 + k]  = xrow[32 + k];
        nxf[16 + k] = (quad < 2) ? xrow[64 + k] : 0.f;
    }
    unsigned short hv[4] = {0, 0, 0, 0};

    __syncthreads();

    for (int t = 0; t < T_; ++t) {
        const unsigned short* sr = sH[t & 1];
        unsigned short*       sw = sH[(t + 1) & 1];

        // A-fragments: h(t) from LDS, x(t) packed from prefetched f32
        short8 ah[4];
        #pragma unroll
        for (int kt = 0; kt < 4; ++kt)
            ah[kt] = *(const short8*)(sr + m16 * 136 + kt * 32 + quad * 8);
        short8 ax0 = pack8(nxf), ax1 = pack8(nxf + 8);
        short8 ax2 = (quad < 2) ? pack8(nxf + 16) : zero8;

        // store th(t-1) now: drain overlaps this step's MFMA phase
        if (t > 0) {
            #pragma unroll
            for (int r = 0; r < 4; ++r)
                th[obase[r] + (unsigned)(t - 1) * (NOTES_ * H_)] = hv[r];
        }
        // prefetch x(t+1) f32
        if (t + 1 < T_) {
            const float* xp = xrow + (t + 1) * IN_;
            #pragma unroll
            for (int k = 0; k < 8; ++k) {
                nxf[k]     = xp[k];
                nxf[8 + k] = xp[32 + k];
                if (quad < 2) nxf[16 + k] = xp[64 + k];
            }
        }

        f32x4 acc[4];
        #pragma unroll
        for (int g = 0; g < 4; ++g) {
            acc[g] = (f32x4){0.f, 0.f, 0.f, 0.f};
            acc[g] = __builtin_amdgcn_mfma_f32_16x16x32_bf16(ax0, wf[g][0], acc[g], 0, 0, 0);
            acc[g] = __builtin_amdgcn_mfma_f32_16x16x32_bf16(ax1, wf[g][1], acc[g], 0, 0, 0);
            acc[g] = __builtin_amdgcn_mfma_f32_16x16x32_bf16(ax2, wf[g][2], acc[g], 0, 0, 0);
            #pragma unroll
            for (int kt = 0; kt < 4; ++kt)
                acc[g] = __builtin_amdgcn_mfma_f32_16x16x32_bf16(ah[kt], hf[g][kt], acc[g], 0, 0, 0);
        }

        // register-only elementwise: rows quad*4+r, col c
        #pragma unroll
        for (int r = 0; r < 4; ++r) {
            const float gi = acc[0][r] + b_i;
            const float gf = acc[1][r] + b_f;
            const float gg = acc[2][r] + b_g;
            const float go = acc[3][r] + b_o;
            const float cf = sigm(gf) * cst[r] + sigm(gi) * tanh_(gg);
            cst[r] = cf;
            hv[r] = f2bf(sigm(go) * tanh_(cf));
            sw[(quad * 4 + r) * 136 + c] = hv[r];
        }

        __syncthreads();   // h(t+1) visible; nxf long in flight; th drained
    }
    #pragma unroll
    for (int r = 0; r < 4; ++r)
        th[obase[r] + (unsigned)(T_ - 1) * (NOTES_ * H_)] = hv[r];
}

// ---------------------------------------------------------------------------
// Phase C (MFMA): Gn[row][g] = th[row]·Wih_n[g] + bih_n[g] + bhh_n[g]
// 1664 blocks x 4 waves x 3 tiles = 19968 tiles of 16 rows.
// ---------------------------------------------------------------------------
__global__ __launch_bounds__(256) void gn_kernel(
    const unsigned short* __restrict__ th,    // [NROWS][128] bf16
    const float* __restrict__ Wih,            // [8][128] f32
    const float* __restrict__ bih,            // [8] f32
    const float* __restrict__ bhh,            // [8] f32
    float* __restrict__ Gn)                   // [NROWS][8] f32
{
    const int tid  = threadIdx.x;
    const int wave = tid >> 6, lane = tid & 63;
    const int m16  = lane & 15, quad = lane >> 4;
    const int wid  = blockIdx.x * 4 + wave;

    const short8 zero8 = (short8){0,0,0,0,0,0,0,0};
    short8 bw[4];   // B[k][n]: n = m16 (gate, 8 valid), k = kt*32 + quad*8 + j
    #pragma unroll
    for (int kt = 0; kt < 4; ++kt)
        bw[kt] = (m16 < 8) ? pack8(Wih + m16 * H_ + kt * 32 + quad * 8) : zero8;
    const float bsum = (m16 < 8) ? (bih[m16] + bhh[m16]) : 0.f;

    #pragma unroll
    for (int it = 0; it < 3; ++it) {
        const int tile = wid * 3 + it;
        const size_t r0 = (size_t)tile * 16;
        const unsigned short* ap = th + (r0 + m16) * H_ + quad * 8;
        f32x4 acc = (f32x4){0.f, 0.f, 0.f, 0.f};
        #pragma unroll
        for (int kt = 0; kt < 4; ++kt)
            acc = __builtin_amdgcn_mfma_f32_16x16x32_bf16(
                *(const short8*)(ap + kt * 32), bw[kt], acc, 0, 0, 0);
        if (m16 < 8) {
            #pragma unroll
            for (int r = 0; r < 4; ++r)
                Gn[(r0 + quad * 4 + r) * 8 + m16] = acc[r] + bsum;
        }
    }
}

// ---------------------------------------------------------------------------
// Phase D: note-LSTM recurrence on precomputed pre-activations.
// One thread per (b,t) sequence; next-n load prefetched.
// ---------------------------------------------------------------------------
__global__ __launch_bounds__(128) void note_out_kernel(
    const float* __restrict__ Gn,    // [SEQ2_][NOTES][8] f32
    const float* __restrict__ Whh,   // [8][2] f32
    float* __restrict__ out)         // [B][T][156] f32
{
    const int q = blockIdx.x * 128 + threadIdx.x;
    if (q >= SEQ2_) return;

    float w0[8], w1[8];
    #pragma unroll
    for (int g = 0; g < 8; ++g) { w0[g] = Whh[g * 2]; w1[g] = Whh[g * 2 + 1]; }

    const float* gp = Gn + (size_t)q * (NOTES_ * 8);
    float* op = out + (size_t)q * (NOTES_ * 2);

    float h0 = 0.f, h1 = 0.f, c0 = 0.f, c1 = 0.f;
    f32x4 ga = *(const f32x4*)(gp);
    f32x4 gb = *(const f32x4*)(gp + 4);
    for (int n = 0; n < NOTES_; ++n) {
        f32x4 na, nb;
        if (n + 1 < NOTES_) {
            na = *(const f32x4*)(gp + (n + 1) * 8);
            nb = *(const f32x4*)(gp + (n + 1) * 8 + 4);
        }
        const float i0 = ga[0] + w0[0] * h0 + w1[0] * h1;
        const float i1 = ga[1] + w0[1] * h0 + w1[1] * h1;
        const float f0 = ga[2] + w0[2] * h0 + w1[2] * h1;
        const float f1 = ga[3] + w0[3] * h0 + w1[3] * h1;
        const float g0 = gb[0] + w0[4] * h0 + w1[4] * h1;
        const float g1 = gb[1] + w0[5] * h0 + w1[5] * h1;
        const float o0 = gb[2] + w0[6] * h0 + w1[6] * h1;
        const float o1 = gb[3] + w0[7] * h0 + w1[7] * h1;
        c0 = sigm(f0) * c0 + sigm(i0) * tanh_(g0);
        c1 = sigm(f1) * c1 + sigm(i1) * tanh_(g1);
        h0 = sigm(o0) * tanh_(c0);
        h1 = sigm(o1) * tanh_(c1);
        op[n * 2 + 0] = h0;
        op[n * 2 + 1] = h1;
        ga = na; gb = nb;
    }
}

extern "C" void kernel_launch(void* const* d_in, const int* in_sizes, int n_in,
                              void* d_out, int out_size, void* d_ws, size_t ws_size,
                              hipStream_t stream) {
    const float* x     = (const float*)d_in[0];
    const float* Wih_t = (const float*)d_in[1];
    const float* Whh_t = (const float*)d_in[2];
    const float* bih_t = (const float*)d_in[3];
    const float* bhh_t = (const float*)d_in[4];
    const float* Wih_n = (const float*)d_in[5];
    const float* Whh_n = (const float*)d_in[6];
    const float* bih_n = (const float*)d_in[7];
    const float* bhh_n = (const float*)d_in[8];
    float* out = (float*)d_out;

    const size_t th_bytes = (size_t)NROWS * H_ * 2;         // 81.8 MB
    unsigned short* th = (unsigned short*)d_ws;
    float* Gn = (float*)((char*)d_ws + th_bytes);           // +10.2 MB

    time_lstm_kernel<<<NBLK1, 512, 0, stream>>>(x, Wih_t, Whh_t, bih_t, bhh_t, th);
    gn_kernel<<<1664, 256, 0, stream>>>(th, Wih_n, bih_n, bhh_n, Gn);
    note_out_kernel<<<SEQ2_ / 128, 128, 0, stream>>>(Gn, Whh_n, out);
}

// Round 6
// 773.939 us; speedup vs baseline: 1.0065x; 1.0065x over previous
//
#include <hip/hip_runtime.h>

// Problem constants
#define B_     32
#define NOTES_ 78
#define T_     128
#define IN_    80
#define H_     128
#define NSEQ_  (B_*NOTES_)    // 2496
#define MBLK   16             // sequences per block (stage 1)
#define NBLK1  (NSEQ_/MBLK)   // 156
#define SEQ2_  (B_*T_)        // 4096 note-LSTM sequences
#define NROWS  (SEQ2_*NOTES_) // 319488 rows of th

typedef __attribute__((ext_vector_type(8))) short short8;   // 8 x bf16 (4 VGPRs)
typedef __attribute__((ext_vector_type(4))) float f32x4;

__device__ __forceinline__ float bf2f(unsigned short v) {
    unsigned u = ((unsigned)v) << 16; float f; __builtin_memcpy(&f, &u, 4); return f;
}
__device__ __forceinline__ unsigned short f2bf(float f) {
    unsigned u; __builtin_memcpy(&u, &f, 4);
    u += 0x7fffu + ((u >> 16) & 1u);          // RNE
    return (unsigned short)(u >> 16);
}
__device__ __forceinline__ short8 pack8(const float* p) {
    short8 r;
    #pragma unroll
    for (int k = 0; k < 8; ++k) r[k] = (short)f2bf(p[k]);
    return r;
}
// v_rcp_f32-based sigmoid/tanh: ~1 ulp rcp, avoids IEEE divide sequences
__device__ __forceinline__ float sigm(float x) {
    return __builtin_amdgcn_rcpf(1.f + __expf(-x));
}
__device__ __forceinline__ float tanh_(float x) {
    return 2.f * __builtin_amdgcn_rcpf(1.f + __expf(-2.f * x)) - 1.f;
}

// ---------------------------------------------------------------------------
// Time LSTM. One block (8 waves, 512 thr) owns MBLK=16 sequences for all T.
// Wave w owns h-cols [16w,16w+16): its 4 MFMA col-tiles are the i/f/g/o gate
// tiles of those cols, so after the MFMA phase thread (m16,quad) holds all 4
// gates for h-col 16w+m16, rows quad*4..+3 — elementwise is register-only.
//
// __launch_bounds__(512, 1): 8-wave block forces 2 waves/SIMD; the 1 gives
// the allocator the full 256 arch-VGPR budget so the 112 weight-frag VGPRs
// stay as direct MFMA operands (R5's (512,2) capped at 128 and the compiler
// bounced weights through AGPRs with v_accvgpr_read before every MFMA —
// +400 VALU cyc/wave/step, 2x regression).
// ---------------------------------------------------------------------------
__global__ __launch_bounds__(512, 1) void time_lstm_kernel(
    const float* __restrict__ x,     // [NSEQ][T][IN] f32
    const float* __restrict__ Wih,   // [512][80]  f32
    const float* __restrict__ Whh,   // [512][128] f32
    const float* __restrict__ bih,   // [512] f32
    const float* __restrict__ bhh,   // [512] f32
    unsigned short* __restrict__ th) // [B][T][NOTES][H] bf16 (ws)
{
    __shared__ unsigned short sH[2][MBLK * 136];   // ping-pong, stride 136

    const int tid  = threadIdx.x;
    const int wave = tid >> 6, lane = tid & 63;
    const int m16  = lane & 15, quad = lane >> 4;
    const int seq0 = blockIdx.x * MBLK;
    const int c    = wave * 16 + m16;              // h-col owned by this thread

    for (int i = tid; i < 2 * MBLK * 136; i += 512)
        ((unsigned short*)sH)[i] = 0;              // h0 = 0 (both buffers)

    // ---- weight B-fragments: 4 gate tiles x (3+4) K-frags = 28 (112 VGPR) --
    const short8 zero8 = (short8){0,0,0,0,0,0,0,0};
    short8 wf[4][3], hf[4][4];
    #pragma unroll
    for (int g = 0; g < 4; ++g) {
        const int n = g * 128 + c;
        #pragma unroll
        for (int kt = 0; kt < 3; ++kt) {
            const int k = kt * 32 + quad * 8;
            wf[g][kt] = (k < IN_) ? pack8(Wih + n * IN_ + k) : zero8;
        }
        #pragma unroll
        for (int kt = 0; kt < 4; ++kt)
            hf[g][kt] = pack8(Whh + n * H_ + kt * 32 + quad * 8);
    }

    const float b_i = bih[      c] + bhh[      c];
    const float b_f = bih[128 + c] + bhh[128 + c];
    const float b_g = bih[256 + c] + bhh[256 + c];
    const float b_o = bih[384 + c] + bhh[384 + c];

    float    cst[4] = {0.f, 0.f, 0.f, 0.f};
    unsigned obase[4];
    #pragma unroll
    for (int r = 0; r < 4; ++r) {
        const int sq = seq0 + quad * 4 + r;
        const int bb = sq / NOTES_;
        const int nn = sq - bb * NOTES_;
        obase[r] = (unsigned)bb * (T_ * NOTES_ * H_) + (unsigned)nn * H_ + (unsigned)c;
    }

    // x rows for A-fragments: row m16 (seq seq0+m16), k = quad*8 (+0/32/64)
    const float* xrow = x + (size_t)(seq0 + m16) * T_ * IN_ + quad * 8;

    // load x(0) as f32 (packed at use)
    float nxf[24];
    #pragma unroll
    for (int k = 0; k < 8; ++k) {
        nxf[k]      = xrow[k];
        nxf[8 + k]  = xrow[32 + k];
        nxf[16 + k] = (quad < 2) ? xrow[64 + k] : 0.f;
    }
    unsigned short hv[4] = {0, 0, 0, 0};

    __syncthreads();

    for (int t = 0; t < T_; ++t) {
        const unsigned short* sr = sH[t & 1];
        unsigned short*       sw = sH[(t + 1) & 1];

        // A-fragments: h(t) from LDS, x(t) packed from prefetched f32
        short8 ah[4];
        #pragma unroll
        for (int kt = 0; kt < 4; ++kt)
            ah[kt] = *(const short8*)(sr + m16 * 136 + kt * 32 + quad * 8);
        short8 ax0 = pack8(nxf), ax1 = pack8(nxf + 8);
        short8 ax2 = (quad < 2) ? pack8(nxf + 16) : zero8;

        // store th(t-1) now: drain overlaps this step's MFMA phase
        if (t > 0) {
            #pragma unroll
            for (int r = 0; r < 4; ++r)
                th[obase[r] + (unsigned)(t - 1) * (NOTES_ * H_)] = hv[r];
        }
        // prefetch x(t+1) f32
        if (t + 1 < T_) {
            const float* xp = xrow + (t + 1) * IN_;
            #pragma unroll
            for (int k = 0; k < 8; ++k) {
                nxf[k]     = xp[k];
                nxf[8 + k] = xp[32 + k];
                if (quad < 2) nxf[16 + k] = xp[64 + k];
            }
        }

        f32x4 acc[4];
        #pragma unroll
        for (int g = 0; g < 4; ++g) {
            acc[g] = (f32x4){0.f, 0.f, 0.f, 0.f};
            acc[g] = __builtin_amdgcn_mfma_f32_16x16x32_bf16(ax0, wf[g][0], acc[g], 0, 0, 0);
            acc[g] = __builtin_amdgcn_mfma_f32_16x16x32_bf16(ax1, wf[g][1], acc[g], 0, 0, 0);
            acc[g] = __builtin_amdgcn_mfma_f32_16x16x32_bf16(ax2, wf[g][2], acc[g], 0, 0, 0);
            #pragma unroll
            for (int kt = 0; kt < 4; ++kt)
                acc[g] = __builtin_amdgcn_mfma_f32_16x16x32_bf16(ah[kt], hf[g][kt], acc[g], 0, 0, 0);
        }

        // register-only elementwise: rows quad*4+r, col c
        #pragma unroll
        for (int r = 0; r < 4; ++r) {
            const float gi = acc[0][r] + b_i;
            const float gf = acc[1][r] + b_f;
            const float gg = acc[2][r] + b_g;
            const float go = acc[3][r] + b_o;
            const float cf = sigm(gf) * cst[r] + sigm(gi) * tanh_(gg);
            cst[r] = cf;
            hv[r] = f2bf(sigm(go) * tanh_(cf));
            sw[(quad * 4 + r) * 136 + c] = hv[r];
        }

        __syncthreads();   // h(t+1) visible; nxf long in flight; th drained
    }
    #pragma unroll
    for (int r = 0; r < 4; ++r)
        th[obase[r] + (unsigned)(T_ - 1) * (NOTES_ * H_)] = hv[r];
}

// ---------------------------------------------------------------------------
// Phase C (MFMA): Gn[row][g] = th[row]·Wih_n[g] + bih_n[g] + bhh_n[g]
// 1664 blocks x 4 waves x 3 tiles = 19968 tiles of 16 rows.
// ---------------------------------------------------------------------------
__global__ __launch_bounds__(256) void gn_kernel(
    const unsigned short* __restrict__ th,    // [NROWS][128] bf16
    const float* __restrict__ Wih,            // [8][128] f32
    const float* __restrict__ bih,            // [8] f32
    const float* __restrict__ bhh,            // [8] f32
    float* __restrict__ Gn)                   // [NROWS][8] f32
{
    const int tid  = threadIdx.x;
    const int wave = tid >> 6, lane = tid & 63;
    const int m16  = lane & 15, quad = lane >> 4;
    const int wid  = blockIdx.x * 4 + wave;

    const short8 zero8 = (short8){0,0,0,0,0,0,0,0};
    short8 bw[4];   // B[k][n]: n = m16 (gate, 8 valid), k = kt*32 + quad*8 + j
    #pragma unroll
    for (int kt = 0; kt < 4; ++kt)
        bw[kt] = (m16 < 8) ? pack8(Wih + m16 * H_ + kt * 32 + quad * 8) : zero8;
    const float bsum = (m16 < 8) ? (bih[m16] + bhh[m16]) : 0.f;

    #pragma unroll
    for (int it = 0; it < 3; ++it) {
        const int tile = wid * 3 + it;
        const size_t r0 = (size_t)tile * 16;
        const unsigned short* ap = th + (r0 + m16) * H_ + quad * 8;
        f32x4 acc = (f32x4){0.f, 0.f, 0.f, 0.f};
        #pragma unroll
        for (int kt = 0; kt < 4; ++kt)
            acc = __builtin_amdgcn_mfma_f32_16x16x32_bf16(
                *(const short8*)(ap + kt * 32), bw[kt], acc, 0, 0, 0);
        if (m16 < 8) {
            #pragma unroll
            for (int r = 0; r < 4; ++r)
                Gn[(r0 + quad * 4 + r) * 8 + m16] = acc[r] + bsum;
        }
    }
}

// ---------------------------------------------------------------------------
// Phase D: note-LSTM recurrence on precomputed pre-activations.
// One thread per (b,t) sequence; next-n load prefetched.
// ---------------------------------------------------------------------------
__global__ __launch_bounds__(128) void note_out_kernel(
    const float* __restrict__ Gn,    // [SEQ2_][NOTES][8] f32
    const float* __restrict__ Whh,   // [8][2] f32
    float* __restrict__ out)         // [B][T][156] f32
{
    const int q = blockIdx.x * 128 + threadIdx.x;
    if (q >= SEQ2_) return;

    float w0[8], w1[8];
    #pragma unroll
    for (int g = 0; g < 8; ++g) { w0[g] = Whh[g * 2]; w1[g] = Whh[g * 2 + 1]; }

    const float* gp = Gn + (size_t)q * (NOTES_ * 8);
    float* op = out + (size_t)q * (NOTES_ * 2);

    float h0 = 0.f, h1 = 0.f, c0 = 0.f, c1 = 0.f;
    f32x4 ga = *(const f32x4*)(gp);
    f32x4 gb = *(const f32x4*)(gp + 4);
    for (int n = 0; n < NOTES_; ++n) {
        f32x4 na, nb;
        if (n + 1 < NOTES_) {
            na = *(const f32x4*)(gp + (n + 1) * 8);
            nb = *(const f32x4*)(gp + (n + 1) * 8 + 4);
        }
        const float i0 = ga[0] + w0[0] * h0 + w1[0] * h1;
        const float i1 = ga[1] + w0[1] * h0 + w1[1] * h1;
        const float f0 = ga[2] + w0[2] * h0 + w1[2] * h1;
        const float f1 = ga[3] + w0[3] * h0 + w1[3] * h1;
        const float g0 = gb[0] + w0[4] * h0 + w1[4] * h1;
        const float g1 = gb[1] + w0[5] * h0 + w1[5] * h1;
        const float o0 = gb[2] + w0[6] * h0 + w1[6] * h1;
        const float o1 = gb[3] + w0[7] * h0 + w1[7] * h1;
        c0 = sigm(f0) * c0 + sigm(i0) * tanh_(g0);
        c1 = sigm(f1) * c1 + sigm(i1) * tanh_(g1);
        h0 = sigm(o0) * tanh_(c0);
        h1 = sigm(o1) * tanh_(c1);
        op[n * 2 + 0] = h0;
        op[n * 2 + 1] = h1;
        ga = na; gb = nb;
    }
}

extern "C" void kernel_launch(void* const* d_in, const int* in_sizes, int n_in,
                              void* d_out, int out_size, void* d_ws, size_t ws_size,
                              hipStream_t stream) {
    const float* x     = (const float*)d_in[0];
    const float* Wih_t = (const float*)d_in[1];
    const float* Whh_t = (const float*)d_in[2];
    const float* bih_t = (const float*)d_in[3];
    const float* bhh_t = (const float*)d_in[4];
    const float* Wih_n = (const float*)d_in[5];
    const float* Whh_n = (const float*)d_in[6];
    const float* bih_n = (const float*)d_in[7];
    const float* bhh_n = (const float*)d_in[8];
    float* out = (float*)d_out;

    const size_t th_bytes = (size_t)NROWS * H_ * 2;         // 81.8 MB
    unsigned short* th = (unsigned short*)d_ws;
    float* Gn = (float*)((char*)d_ws + th_bytes);           // +10.2 MB

    time_lstm_kernel<<<NBLK1, 512, 0, stream>>>(x, Wih_t, Whh_t, bih_t, bhh_t, th);
    gn_kernel<<<1664, 256, 0, stream>>>(th, Wih_n, bih_n, bhh_n, Gn);
    note_out_kernel<<<SEQ2_ / 128, 128, 0, stream>>>(Gn, Whh_n, out);
}

// Round 7
// 758.824 us; speedup vs baseline: 1.0266x; 1.0199x over previous
//
#include <hip/hip_runtime.h>

// Problem constants
#define B_     32
#define NOTES_ 78
#define T_     128
#define IN_    80
#define H_     128
#define NSEQ_  (B_*NOTES_)    // 2496
#define MBLK   16             // sequences per block (stage 1)
#define NBLK1  (NSEQ_/MBLK)   // 156
#define SEQ2_  (B_*T_)        // 4096 note-LSTM sequences
#define NROWS  (SEQ2_*NOTES_) // 319488 rows of th
#define HSTR   136            // hist row stride (elems): 128 + 8 pad

typedef __attribute__((ext_vector_type(8))) short short8;   // 8 x bf16 (4 VGPRs)
typedef __attribute__((ext_vector_type(4))) float f32x4;

__device__ __forceinline__ float bf2f(unsigned short v) {
    unsigned u = ((unsigned)v) << 16; float f; __builtin_memcpy(&f, &u, 4); return f;
}
__device__ __forceinline__ unsigned short f2bf(float f) {
    unsigned u; __builtin_memcpy(&u, &f, 4);
    u += 0x7fffu + ((u >> 16) & 1u);          // RNE
    return (unsigned short)(u >> 16);
}
__device__ __forceinline__ short8 pack8(const float* p) {
    short8 r;
    #pragma unroll
    for (int k = 0; k < 8; ++k) r[k] = (short)f2bf(p[k]);
    return r;
}
// v_rcp_f32-based sigmoid/tanh: avoids IEEE divide sequences
__device__ __forceinline__ float sigm(float x) {
    return __builtin_amdgcn_rcpf(1.f + __expf(-x));
}
__device__ __forceinline__ float tanh_(float x) {
    return 2.f * __builtin_amdgcn_rcpf(1.f + __expf(-2.f * x)) - 1.f;
}

// ---------------------------------------------------------------------------
// Time LSTM. One block (8 waves, 512 thr) owns MBLK=16 sequences for all T.
// Wave w owns h-cols [16w,16w+16): after the MFMA phase thread (m16,quad)
// holds all 4 gates for h-col 16w+m16, rows quad*4..+3 — register elementwise.
//
// KEY CHANGE (R7): no global stores inside the per-step barrier domain.
// __syncthreads emits s_waitcnt vmcnt(0) (m97), so R4-R6's per-step scattered
// th stores forced an HBM-ack drain every step — the dominant stall. Now h
// goes to an LDS history buffer hist[16][MBLK][HSTR] that (a) serves the
// recurrence reads (slot (t-1)%16 holds h(t)) and (b) is flushed to global th
// in one coalesced 64 KB burst every 16 steps — one vmcnt drain per 16 steps.
// ---------------------------------------------------------------------------
__global__ __launch_bounds__(512, 1) void time_lstm_kernel(
    const float* __restrict__ x,     // [NSEQ][T][IN] f32
    const float* __restrict__ Wih,   // [512][80]  f32
    const float* __restrict__ Whh,   // [512][128] f32
    const float* __restrict__ bih,   // [512] f32
    const float* __restrict__ bhh,   // [512] f32
    unsigned short* __restrict__ th) // [B][T][NOTES][H] bf16 (ws)
{
    __shared__ unsigned short hist[16 * MBLK * HSTR];   // 69.6 KB

    const int tid  = threadIdx.x;
    const int wave = tid >> 6, lane = tid & 63;
    const int m16  = lane & 15, quad = lane >> 4;
    const int seq0 = blockIdx.x * MBLK;
    const int c    = wave * 16 + m16;              // h-col owned by this thread

    // zero slot 15 (read as h(0) at t=0)
    for (int i = tid; i < MBLK * HSTR; i += 512)
        hist[15 * MBLK * HSTR + i] = 0;

    // ---- weight B-fragments: 4 gate tiles x (3+4) K-frags = 28 ----
    const short8 zero8 = (short8){0,0,0,0,0,0,0,0};
    short8 wf[4][3], hf[4][4];
    #pragma unroll
    for (int g = 0; g < 4; ++g) {
        const int n = g * 128 + c;
        #pragma unroll
        for (int kt = 0; kt < 3; ++kt) {
            const int k = kt * 32 + quad * 8;
            wf[g][kt] = (k < IN_) ? pack8(Wih + n * IN_ + k) : zero8;
        }
        #pragma unroll
        for (int kt = 0; kt < 4; ++kt)
            hf[g][kt] = pack8(Whh + n * H_ + kt * 32 + quad * 8);
    }

    const float b_i = bih[      c] + bhh[      c];
    const float b_f = bih[128 + c] + bhh[128 + c];
    const float b_g = bih[256 + c] + bhh[256 + c];
    const float b_o = bih[384 + c] + bhh[384 + c];

    float cst[4] = {0.f, 0.f, 0.f, 0.f};

    // x rows for A-fragments: row m16 (seq seq0+m16), k = quad*8 (+0/32/64)
    const float* xrow = x + (size_t)(seq0 + m16) * T_ * IN_ + quad * 8;

    // load x(0) as f32 (packed to bf16 at use)
    float nxf[24];
    #pragma unroll
    for (int k = 0; k < 8; ++k) {
        nxf[k]      = xrow[k];
        nxf[8 + k]  = xrow[32 + k];
        nxf[16 + k] = (quad < 2) ? xrow[64 + k] : 0.f;
    }

    __syncthreads();

    for (int t = 0; t < T_; ++t) {
        // A-fragments: h(t) from hist slot (t-1)%16, x(t) packed from f32
        const int sp = (t + 15) & 15;
        short8 ah[4];
        #pragma unroll
        for (int kt = 0; kt < 4; ++kt)
            ah[kt] = *(const short8*)(hist + (sp * MBLK + m16) * HSTR + kt * 32 + quad * 8);
        short8 ax0 = pack8(nxf), ax1 = pack8(nxf + 8);
        short8 ax2 = (quad < 2) ? pack8(nxf + 16) : zero8;

        // prefetch x(t+1) f32 — long in flight; drains at a far barrier
        if (t + 1 < T_) {
            const float* xp = xrow + (t + 1) * IN_;
            #pragma unroll
            for (int k = 0; k < 8; ++k) {
                nxf[k]     = xp[k];
                nxf[8 + k] = xp[32 + k];
                if (quad < 2) nxf[16 + k] = xp[64 + k];
            }
        }

        f32x4 acc[4];
        #pragma unroll
        for (int g = 0; g < 4; ++g) {
            acc[g] = (f32x4){0.f, 0.f, 0.f, 0.f};
            acc[g] = __builtin_amdgcn_mfma_f32_16x16x32_bf16(ax0, wf[g][0], acc[g], 0, 0, 0);
            acc[g] = __builtin_amdgcn_mfma_f32_16x16x32_bf16(ax1, wf[g][1], acc[g], 0, 0, 0);
            acc[g] = __builtin_amdgcn_mfma_f32_16x16x32_bf16(ax2, wf[g][2], acc[g], 0, 0, 0);
            #pragma unroll
            for (int kt = 0; kt < 4; ++kt)
                acc[g] = __builtin_amdgcn_mfma_f32_16x16x32_bf16(ah[kt], hf[g][kt], acc[g], 0, 0, 0);
        }

        // register-only elementwise: rows quad*4+r, col c -> hist slot t%16
        const int sw = t & 15;
        #pragma unroll
        for (int r = 0; r < 4; ++r) {
            const float gi = acc[0][r] + b_i;
            const float gf = acc[1][r] + b_f;
            const float gg = acc[2][r] + b_g;
            const float go = acc[3][r] + b_o;
            const float cf = sigm(gf) * cst[r] + sigm(gi) * tanh_(gg);
            cst[r] = cf;
            hist[(sw * MBLK + quad * 4 + r) * HSTR + c] = f2bf(sigm(go) * tanh_(cf));
        }

        __syncthreads();   // LDS-only drain (plus in-flight x prefetch)

        if ((t & 15) == 15) {
            // flush th[t-15 .. t] for this block's 16 seqs: 256 rows x 256 B.
            // cid = it*512+tid; 16 consecutive tids cover one row (coalesced).
            const int t0 = t - 15;
            #pragma unroll
            for (int it = 0; it < 8; ++it) {
                const int cid = it * 512 + tid;
                const int row = cid >> 4;            // tt*16 + s
                const int off = cid & 15;            // 16B chunk within row
                const int tt  = row >> 4, s = row & 15;
                const int seq = seq0 + s;
                const int bb  = seq / NOTES_;
                const int nn  = seq - bb * NOTES_;
                const short8 v = *(const short8*)(hist + row * HSTR + off * 8);
                *(short8*)(th + ((size_t)(bb * T_ + t0 + tt) * NOTES_ + nn) * H_ + off * 8) = v;
            }
            __syncthreads();   // hist slots reusable; flush stores drain here
        }
    }
}

// ---------------------------------------------------------------------------
// Phase C (MFMA): Gn[row][g] = th[row]·Wih_n[g] + bih_n[g] + bhh_n[g]
// 1664 blocks x 4 waves x 3 tiles = 19968 tiles of 16 rows.
// ---------------------------------------------------------------------------
__global__ __launch_bounds__(256) void gn_kernel(
    const unsigned short* __restrict__ th,    // [NROWS][128] bf16
    const float* __restrict__ Wih,            // [8][128] f32
    const float* __restrict__ bih,            // [8] f32
    const float* __restrict__ bhh,            // [8] f32
    float* __restrict__ Gn)                   // [NROWS][8] f32
{
    const int tid  = threadIdx.x;
    const int wave = tid >> 6, lane = tid & 63;
    const int m16  = lane & 15, quad = lane >> 4;
    const int wid  = blockIdx.x * 4 + wave;

    const short8 zero8 = (short8){0,0,0,0,0,0,0,0};
    short8 bw[4];   // B[k][n]: n = m16 (gate, 8 valid), k = kt*32 + quad*8 + j
    #pragma unroll
    for (int kt = 0; kt < 4; ++kt)
        bw[kt] = (m16 < 8) ? pack8(Wih + m16 * H_ + kt * 32 + quad * 8) : zero8;
    const float bsum = (m16 < 8) ? (bih[m16] + bhh[m16]) : 0.f;

    #pragma unroll
    for (int it = 0; it < 3; ++it) {
        const int tile = wid * 3 + it;
        const size_t r0 = (size_t)tile * 16;
        const unsigned short* ap = th + (r0 + m16) * H_ + quad * 8;
        f32x4 acc = (f32x4){0.f, 0.f, 0.f, 0.f};
        #pragma unroll
        for (int kt = 0; kt < 4; ++kt)
            acc = __builtin_amdgcn_mfma_f32_16x16x32_bf16(
                *(const short8*)(ap + kt * 32), bw[kt], acc, 0, 0, 0);
        if (m16 < 8) {
            #pragma unroll
            for (int r = 0; r < 4; ++r)
                Gn[(r0 + quad * 4 + r) * 8 + m16] = acc[r] + bsum;
        }
    }
}

// ---------------------------------------------------------------------------
// Phase D: note-LSTM recurrence on precomputed pre-activations.
// One thread per (b,t) sequence; next-n load prefetched.
// ---------------------------------------------------------------------------
__global__ __launch_bounds__(128) void note_out_kernel(
    const float* __restrict__ Gn,    // [SEQ2_][NOTES][8] f32
    const float* __restrict__ Whh,   // [8][2] f32
    float* __restrict__ out)         // [B][T][156] f32
{
    const int q = blockIdx.x * 128 + threadIdx.x;
    if (q >= SEQ2_) return;

    float w0[8], w1[8];
    #pragma unroll
    for (int g = 0; g < 8; ++g) { w0[g] = Whh[g * 2]; w1[g] = Whh[g * 2 + 1]; }

    const float* gp = Gn + (size_t)q * (NOTES_ * 8);
    float* op = out + (size_t)q * (NOTES_ * 2);

    float h0 = 0.f, h1 = 0.f, c0 = 0.f, c1 = 0.f;
    f32x4 ga = *(const f32x4*)(gp);
    f32x4 gb = *(const f32x4*)(gp + 4);
    for (int n = 0; n < NOTES_; ++n) {
        f32x4 na, nb;
        if (n + 1 < NOTES_) {
            na = *(const f32x4*)(gp + (n + 1) * 8);
            nb = *(const f32x4*)(gp + (n + 1) * 8 + 4);
        }
        const float i0 = ga[0] + w0[0] * h0 + w1[0] * h1;
        const float i1 = ga[1] + w0[1] * h0 + w1[1] * h1;
        const float f0 = ga[2] + w0[2] * h0 + w1[2] * h1;
        const float f1 = ga[3] + w0[3] * h0 + w1[3] * h1;
        const float g0 = gb[0] + w0[4] * h0 + w1[4] * h1;
        const float g1 = gb[1] + w0[5] * h0 + w1[5] * h1;
        const float o0 = gb[2] + w0[6] * h0 + w1[6] * h1;
        const float o1 = gb[3] + w0[7] * h0 + w1[7] * h1;
        c0 = sigm(f0) * c0 + sigm(i0) * tanh_(g0);
        c1 = sigm(f1) * c1 + sigm(i1) * tanh_(g1);
        h0 = sigm(o0) * tanh_(c0);
        h1 = sigm(o1) * tanh_(c1);
        op[n * 2 + 0] = h0;
        op[n * 2 + 1] = h1;
        ga = na; gb = nb;
    }
}

extern "C" void kernel_launch(void* const* d_in, const int* in_sizes, int n_in,
                              void* d_out, int out_size, void* d_ws, size_t ws_size,
                              hipStream_t stream) {
    const float* x     = (const float*)d_in[0];
    const float* Wih_t = (const float*)d_in[1];
    const float* Whh_t = (const float*)d_in[2];
    const float* bih_t = (const float*)d_in[3];
    const float* bhh_t = (const float*)d_in[4];
    const float* Wih_n = (const float*)d_in[5];
    const float* Whh_n = (const float*)d_in[6];
    const float* bih_n = (const float*)d_in[7];
    const float* bhh_n = (const float*)d_in[8];
    float* out = (float*)d_out;

    const size_t th_bytes = (size_t)NROWS * H_ * 2;         // 81.8 MB
    unsigned short* th = (unsigned short*)d_ws;
    float* Gn = (float*)((char*)d_ws + th_bytes);           // +10.2 MB

    time_lstm_kernel<<<NBLK1, 512, 0, stream>>>(x, Wih_t, Whh_t, bih_t, bhh_t, th);
    gn_kernel<<<1664, 256, 0, stream>>>(th, Wih_n, bih_n, bhh_n, Gn);
    note_out_kernel<<<SEQ2_ / 128, 128, 0, stream>>>(Gn, Whh_n, out);
}

// Round 8
// 551.425 us; speedup vs baseline: 1.4126x; 1.3761x over previous
//
#include <hip/hip_runtime.h>

// Problem constants
#define B_     32
#define NOTES_ 78
#define T_     128
#define IN_    80
#define H_     128
#define NSEQ_  (B_*NOTES_)    // 2496
#define MBLK   16             // sequences per block (stage 1)
#define NBLK1  (NSEQ_/MBLK)   // 156
#define SEQ2_  (B_*T_)        // 4096 note-LSTM sequences
#define NROWS  (SEQ2_*NOTES_) // 319488 rows
#define XN8    (NSEQ_*T_*IN_/8)
#define SGS    21             // sG stride (floats): gcd(21,32)=1 -> conflict-free

typedef __attribute__((ext_vector_type(8))) short short8;   // 8 x bf16 (4 VGPRs)
typedef __attribute__((ext_vector_type(4))) float f32x4;

__device__ __forceinline__ float bf2f(unsigned short v) {
    unsigned u = ((unsigned)v) << 16; float f; __builtin_memcpy(&f, &u, 4); return f;
}
__device__ __forceinline__ unsigned short f2bf(float f) {
    unsigned u; __builtin_memcpy(&u, &f, 4);
    u += 0x7fffu + ((u >> 16) & 1u);          // RNE
    return (unsigned short)(u >> 16);
}
__device__ __forceinline__ short8 pack8(const float* p) {
    short8 r;
    #pragma unroll
    for (int k = 0; k < 8; ++k) r[k] = (short)f2bf(p[k]);
    return r;
}
__device__ __forceinline__ float sigm(float x) {
    return __builtin_amdgcn_rcpf(1.f + __expf(-x));
}
__device__ __forceinline__ float tanh_(float x) {
    return 2.f * __builtin_amdgcn_rcpf(1.f + __expf(-2.f * x)) - 1.f;
}

// ---------------------------------------------------------------------------
// Phase A: convert x f32 -> bf16
// ---------------------------------------------------------------------------
__global__ __launch_bounds__(256) void xcvt_kernel(
    const float* __restrict__ x, unsigned short* __restrict__ xb)
{
    const int i = blockIdx.x * 256 + threadIdx.x;
    if (i < XN8) {
        short8 v = pack8(x + (size_t)i * 8);
        *(short8*)(xb + (size_t)i * 8) = v;
    }
}

// ---------------------------------------------------------------------------
// Phase B: time LSTM + fused note-gate GEMM. R4's measured-best structure
// (1024 thr / 16 waves / 4 waves/SIMD) with strict work removal:
//  - th is never materialized: a rotating wave (t&15) computes
//    Gn(t-1) = h(t-1)·Wih_n^T + b from its already-loaded ah fragments
//    (identical bf16 values + MFMA chain as the old gn_kernel -> bit-identical).
//  - sG stride 21 (odd) kills the 8-way elementwise bank conflict of R4.
// ---------------------------------------------------------------------------
template<bool XB16>
__global__ __launch_bounds__(1024, 4) void time_lstm_kernel(
    const void* __restrict__ xin,    // [NSEQ][T][IN] bf16 (XB16) or f32
    const float* __restrict__ Wih,   // [512][80]  f32
    const float* __restrict__ Whh,   // [512][128] f32
    const float* __restrict__ bih,   // [512] f32
    const float* __restrict__ bhh,   // [512] f32
    const float* __restrict__ Wihn,  // [8][128] f32
    const float* __restrict__ bihn,  // [8] f32
    const float* __restrict__ bhhn,  // [8] f32
    float* __restrict__ Gn)          // [B][T][NOTES][8] f32 (ws)
{
    __shared__ float sG[512 * SGS];                 // 43.0 KB
    __shared__ unsigned short sH[2][MBLK * 136];    // 8.7 KB ping-pong

    const int tid  = threadIdx.x;
    const int wave = tid >> 6, lane = tid & 63;
    const int m16  = lane & 15, quad = lane >> 4;
    const int seq0 = blockIdx.x * MBLK;
    const int ncol0 = wave * 32;     // wave w owns gate cols [32w, 32w+32)

    for (int i = tid; i < 2 * MBLK * 136; i += 1024)
        ((unsigned short*)sH)[i] = 0;   // h0 = 0 (both buffers)

    // ---- time-LSTM weight B-fragments: 2 col-tiles x (3+4) = 14 frags ----
    const short8 zero8 = (short8){0,0,0,0,0,0,0,0};
    short8 wf[3][2];   // Wih: K padded 80 -> 96
    short8 hf[4][2];   // Whh: K = 128
    #pragma unroll
    for (int nt = 0; nt < 2; ++nt) {
        const int n = ncol0 + nt * 16 + m16;
        #pragma unroll
        for (int kt = 0; kt < 3; ++kt) {
            const int k = kt * 32 + quad * 8;
            wf[kt][nt] = (k < IN_) ? pack8(Wih + n * IN_ + k) : zero8;
        }
        #pragma unroll
        for (int kt = 0; kt < 4; ++kt)
            hf[kt][nt] = pack8(Whh + n * H_ + kt * 32 + quad * 8);
    }

    // ---- note-gate B-fragments (all waves hold them; used every 16th step)
    short8 nf[4];
    #pragma unroll
    for (int kt = 0; kt < 4; ++kt)
        nf[kt] = (m16 < 8) ? pack8(Wihn + m16 * H_ + kt * 32 + quad * 8) : zero8;
    const float nbsum = (m16 < 8) ? (bihn[m16] + bhhn[m16]) : 0.f;
    unsigned gnbase[4];
    #pragma unroll
    for (int r = 0; r < 4; ++r) {
        const int sq = seq0 + quad * 4 + r;
        const int bb = sq / NOTES_;
        const int nn = sq - bb * NOTES_;
        gnbase[r] = ((unsigned)bb * T_ * NOTES_ + (unsigned)nn) * 8 + (unsigned)m16;
    }

    // ---- elementwise mapping: thread owns h-col j, rows mb, mb+1 ----
    const int j  = tid & 127;
    const int mb = (tid >> 7) * 2;
    const float b_i = bih[      j] + bhh[      j];
    const float b_f = bih[128 + j] + bhh[128 + j];
    const float b_g = bih[256 + j] + bhh[256 + j];
    const float b_o = bih[384 + j] + bhh[384 + j];
    float cst[2] = {0.f, 0.f};

    const float* xrf = XB16 ? nullptr
        : ((const float*)xin + (size_t)(seq0 + m16) * T_ * IN_);
    const unsigned short* xrb = XB16
        ? ((const unsigned short*)xin + (size_t)(seq0 + m16) * T_ * IN_) : nullptr;

    short8 ax0, ax1, ax2;
    if (XB16) {
        const unsigned short* p = xrb;
        ax0 = *(const short8*)(p + quad * 8);
        ax1 = *(const short8*)(p + 32 + quad * 8);
        ax2 = (quad < 2) ? *(const short8*)(p + 64 + quad * 8) : zero8;
    } else {
        const float* p = xrf;
        ax0 = pack8(p + quad * 8);
        ax1 = pack8(p + 32 + quad * 8);
        ax2 = (quad < 2) ? pack8(p + 64 + quad * 8) : zero8;
    }

    __syncthreads();

    for (int t = 0; t < T_; ++t) {
        // A-fragments of h(t-input) = hv(t-1) (th row t-1)
        const unsigned short* sr = sH[t & 1];
        short8 ah[4];
        #pragma unroll
        for (int kt = 0; kt < 4; ++kt)
            ah[kt] = *(const short8*)(sr + m16 * 136 + kt * 32 + quad * 8);

        f32x4 acc[2];
        #pragma unroll
        for (int nt = 0; nt < 2; ++nt) {
            acc[nt] = (f32x4){0.f, 0.f, 0.f, 0.f};
            acc[nt] = __builtin_amdgcn_mfma_f32_16x16x32_bf16(ax0, wf[0][nt], acc[nt], 0, 0, 0);
            acc[nt] = __builtin_amdgcn_mfma_f32_16x16x32_bf16(ax1, wf[1][nt], acc[nt], 0, 0, 0);
            acc[nt] = __builtin_amdgcn_mfma_f32_16x16x32_bf16(ax2, wf[2][nt], acc[nt], 0, 0, 0);
            #pragma unroll
            for (int kt = 0; kt < 4; ++kt)
                acc[nt] = __builtin_amdgcn_mfma_f32_16x16x32_bf16(ah[kt], hf[kt][nt], acc[nt], 0, 0, 0);
        }

        // C/D layout: col = lane&15, row = quad*4 + reg
        #pragma unroll
        for (int nt = 0; nt < 2; ++nt) {
            const int c = ncol0 + nt * 16 + m16;
            *(f32x4*)(sG + c * SGS + quad * 4) = acc[nt];
        }

        // fused note-gate GEMM: rotating wave computes Gn(t-1) from ah
        if (wave == (t & 15) && t > 0) {
            f32x4 ga = (f32x4){0.f, 0.f, 0.f, 0.f};
            #pragma unroll
            for (int kt = 0; kt < 4; ++kt)
                ga = __builtin_amdgcn_mfma_f32_16x16x32_bf16(ah[kt], nf[kt], ga, 0, 0, 0);
            if (m16 < 8) {
                #pragma unroll
                for (int r = 0; r < 4; ++r)
                    Gn[gnbase[r] + (unsigned)(t - 1) * (NOTES_ * 8)] = ga[r] + nbsum;
            }
        }

        // prefetch x(t+1)
        if (t + 1 < T_) {
            if (XB16) {
                const unsigned short* p = xrb + (t + 1) * IN_;
                ax0 = *(const short8*)(p + quad * 8);
                ax1 = *(const short8*)(p + 32 + quad * 8);
                if (quad < 2) ax2 = *(const short8*)(p + 64 + quad * 8);
            } else {
                const float* p = xrf + (t + 1) * IN_;
                ax0 = pack8(p + quad * 8);
                ax1 = pack8(p + 32 + quad * 8);
                if (quad < 2) ax2 = pack8(p + 64 + quad * 8);
            }
        }

        __syncthreads();   // barrier#1: gates visible

        float2 vi = *(const float2*)(sG + (0   + j) * SGS + mb);
        float2 vf = *(const float2*)(sG + (128 + j) * SGS + mb);
        float2 vg = *(const float2*)(sG + (256 + j) * SGS + mb);
        float2 vo = *(const float2*)(sG + (384 + j) * SGS + mb);
        unsigned short* sw = sH[(t + 1) & 1];
        #pragma unroll
        for (int mm = 0; mm < 2; ++mm) {
            const float gi = (mm ? vi.y : vi.x) + b_i;
            const float gf = (mm ? vf.y : vf.x) + b_f;
            const float gg = (mm ? vg.y : vg.x) + b_g;
            const float go = (mm ? vo.y : vo.x) + b_o;
            const float cf = sigm(gf) * cst[mm] + sigm(gi) * tanh_(gg);
            cst[mm] = cf;
            sw[(mb + mm) * 136 + j] = f2bf(sigm(go) * tanh_(cf));
        }

        __syncthreads();   // barrier#2: h(t) visible
    }

    // epilogue: Gn(T-1) from h in sH[T_&1] by wave (T_&15)
    if (wave == (T_ & 15)) {
        const unsigned short* sr = sH[T_ & 1];
        short8 ah[4];
        #pragma unroll
        for (int kt = 0; kt < 4; ++kt)
            ah[kt] = *(const short8*)(sr + m16 * 136 + kt * 32 + quad * 8);
        f32x4 ga = (f32x4){0.f, 0.f, 0.f, 0.f};
        #pragma unroll
        for (int kt = 0; kt < 4; ++kt)
            ga = __builtin_amdgcn_mfma_f32_16x16x32_bf16(ah[kt], nf[kt], ga, 0, 0, 0);
        if (m16 < 8) {
            #pragma unroll
            for (int r = 0; r < 4; ++r)
                Gn[gnbase[r] + (unsigned)(T_ - 1) * (NOTES_ * 8)] = ga[r] + nbsum;
        }
    }
}

// ---------------------------------------------------------------------------
// Phase D: note-LSTM recurrence on precomputed pre-activations.
// ---------------------------------------------------------------------------
__global__ __launch_bounds__(128) void note_out_kernel(
    const float* __restrict__ Gn,    // [SEQ2_][NOTES][8] f32
    const float* __restrict__ Whh,   // [8][2] f32
    float* __restrict__ out)         // [B][T][156] f32
{
    const int q = blockIdx.x * 128 + threadIdx.x;
    if (q >= SEQ2_) return;

    float w0[8], w1[8];
    #pragma unroll
    for (int g = 0; g < 8; ++g) { w0[g] = Whh[g * 2]; w1[g] = Whh[g * 2 + 1]; }

    const float* gp = Gn + (size_t)q * (NOTES_ * 8);
    float* op = out + (size_t)q * (NOTES_ * 2);

    float h0 = 0.f, h1 = 0.f, c0 = 0.f, c1 = 0.f;
    f32x4 ga = *(const f32x4*)(gp);
    f32x4 gb = *(const f32x4*)(gp + 4);
    for (int n = 0; n < NOTES_; ++n) {
        f32x4 na, nb;
        if (n + 1 < NOTES_) {
            na = *(const f32x4*)(gp + (n + 1) * 8);
            nb = *(const f32x4*)(gp + (n + 1) * 8 + 4);
        }
        const float i0 = ga[0] + w0[0] * h0 + w1[0] * h1;
        const float i1 = ga[1] + w0[1] * h0 + w1[1] * h1;
        const float f0 = ga[2] + w0[2] * h0 + w1[2] * h1;
        const float f1 = ga[3] + w0[3] * h0 + w1[3] * h1;
        const float g0 = gb[0] + w0[4] * h0 + w1[4] * h1;
        const float g1 = gb[1] + w0[5] * h0 + w1[5] * h1;
        const float o0 = gb[2] + w0[6] * h0 + w1[6] * h1;
        const float o1 = gb[3] + w0[7] * h0 + w1[7] * h1;
        c0 = sigm(f0) * c0 + sigm(i0) * tanh_(g0);
        c1 = sigm(f1) * c1 + sigm(i1) * tanh_(g1);
        h0 = sigm(o0) * tanh_(c0);
        h1 = sigm(o1) * tanh_(c1);
        op[n * 2 + 0] = h0;
        op[n * 2 + 1] = h1;
        ga = na; gb = nb;
    }
}

extern "C" void kernel_launch(void* const* d_in, const int* in_sizes, int n_in,
                              void* d_out, int out_size, void* d_ws, size_t ws_size,
                              hipStream_t stream) {
    const float* x     = (const float*)d_in[0];
    const float* Wih_t = (const float*)d_in[1];
    const float* Whh_t = (const float*)d_in[2];
    const float* bih_t = (const float*)d_in[3];
    const float* bhh_t = (const float*)d_in[4];
    const float* Wih_n = (const float*)d_in[5];
    const float* Whh_n = (const float*)d_in[6];
    const float* bih_n = (const float*)d_in[7];
    const float* bhh_n = (const float*)d_in[8];
    float* out = (float*)d_out;

    const size_t xb_bytes = (size_t)NSEQ_ * T_ * IN_ * 2;   // 51.1 MB
    const size_t gn_bytes = (size_t)NROWS * 8 * 4;          // 10.2 MB

    if (ws_size >= xb_bytes + gn_bytes) {
        unsigned short* xb = (unsigned short*)d_ws;
        float* Gn = (float*)((char*)d_ws + xb_bytes);
        xcvt_kernel<<<(XN8 + 255) / 256, 256, 0, stream>>>(x, xb);
        time_lstm_kernel<true><<<NBLK1, 1024, 0, stream>>>(
            xb, Wih_t, Whh_t, bih_t, bhh_t, Wih_n, bih_n, bhh_n, Gn);
        note_out_kernel<<<SEQ2_ / 128, 128, 0, stream>>>(Gn, Whh_n, out);
    } else {
        float* Gn = (float*)d_ws;   // needs only 10.2 MB
        time_lstm_kernel<false><<<NBLK1, 1024, 0, stream>>>(
            x, Wih_t, Whh_t, bih_t, bhh_t, Wih_n, bih_n, bhh_n, Gn);
        note_out_kernel<<<SEQ2_ / 128, 128, 0, stream>>>(Gn, Whh_n, out);
    }
}